// Round 5
// baseline (382.485 us; speedup 1.0000x reference)
//
#include <hip/hip_runtime.h>
#include <hip/hip_bf16.h>

// AssignAttention: B=16, N=256, S=4096, C=512, H=8, hd=64
// out[b,n,h*64+c] = sum_s softmax_n(q.kT/8)[n,s]/max(rowsum,1) * key[b,s,h*64+c]
// d_out = [out, out_style] (identical copies), fp32.

typedef __attribute__((ext_vector_type(8))) short bf16x8;
typedef __attribute__((ext_vector_type(4))) float f32x4;
typedef unsigned int u32;

__device__ __forceinline__ unsigned short f2bf(float f) {
  union { __hip_bfloat16 h; unsigned short u; } cv;
  cv.h = __float2bfloat16(f);
  return cv.u;
}

__device__ __forceinline__ u32 pkbf(float a, float b) {   // low=bf(a), high=bf(b)
  union { __hip_bfloat162 h; u32 u; } cv;
  cv.h = __float22bfloat162_rn(float2{a, b});
  return cv.u;
}

// async global->LDS, 16B per lane. LDS dest = wave-uniform base + lane*16.
__device__ __forceinline__ void async_copy16(const void* gptr, void* lptr) {
  __builtin_amdgcn_global_load_lds((const __attribute__((address_space(1))) u32*)gptr,
                                   (__attribute__((address_space(3))) u32*)lptr,
                                   16, 0, 0);
}

// ---------------------------------------------------------------- prep: Wt[n][k] = bf16(W[k][n])
__global__ __launch_bounds__(256) void prep_w(const float* __restrict__ Wq,
                                              const float* __restrict__ Wk,
                                              unsigned short* __restrict__ WtQ,
                                              unsigned short* __restrict__ WtK) {
  __shared__ float tile[64][65];
  const int blk = blockIdx.x;
  const float* W = (blk & 1) ? Wk : Wq;
  unsigned short* Wt = (blk & 1) ? WtK : WtQ;
  const int tb = blk >> 1;                     // 0..63
  const int k0 = (tb >> 3) * 64, n0 = (tb & 7) * 64;
  const int t = threadIdx.x;
  const int row = t >> 4, col4 = (t & 15) * 4;
#pragma unroll
  for (int i = 0; i < 4; ++i) {
    int r = i * 16 + row;
    float4 v = *reinterpret_cast<const float4*>(&W[(size_t)(k0 + r) * 512 + n0 + col4]);
    tile[r][col4 + 0] = v.x; tile[r][col4 + 1] = v.y;
    tile[r][col4 + 2] = v.z; tile[r][col4 + 3] = v.w;
  }
  __syncthreads();
#pragma unroll
  for (int i = 0; i < 4; ++i) {
    int r = i * 16 + row;                      // n-local output row
    short4 s;
    s.x = (short)f2bf(tile[col4 + 0][r]);
    s.y = (short)f2bf(tile[col4 + 1][r]);
    s.z = (short)f2bf(tile[col4 + 2][r]);
    s.w = (short)f2bf(tile[col4 + 3][r]);
    *reinterpret_cast<short4*>(&Wt[(size_t)(n0 + r) * 512 + k0 + col4]) = s;
  }
}

// ---------------------------------------------------------------- GEMM: Y[m][n] = bf16( X[m][:] @ Wt[n][:] )
// (unchanged from round 3 — swizzled DMA staging, conflicts verified gone)
__global__ __launch_bounds__(256, 3) void gemm_xw(const float* __restrict__ X,
                                                  const unsigned short* __restrict__ Wt,
                                                  __hip_bfloat16* __restrict__ Y) {
  __shared__ float As[128 * 64];            // 32 KB, swizzled chunk layout
  __shared__ unsigned short Bs[128 * 64];   // 16 KB, swizzled chunk layout
  const int t = threadIdx.x;
  const int wave = t >> 6, lane = t & 63, l15 = lane & 15, quad = lane >> 4;
  const int n0 = blockIdx.x * 128, m0 = blockIdx.y * 128;
  const int wm = (wave >> 1) * 64, wn = (wave & 1) * 64;

  const int a_rl = lane >> 4;                       // 0..3
  const int b_rl = lane >> 3;                       // 0..7
  const int b_cs = (lane & 7) ^ b_rl;               // source chunk (row&7 == b_rl)

  f32x4 acc[4][4];
#pragma unroll
  for (int i = 0; i < 4; ++i)
#pragma unroll
    for (int j = 0; j < 4; ++j) { f32x4 z = {0.f, 0.f, 0.f, 0.f}; acc[i][j] = z; }

  for (int k0 = 0; k0 < 512; k0 += 64) {
    __syncthreads();
    {
      const float* aBase = X + (size_t)m0 * 512 + k0;
#pragma unroll
      for (int o = 0; o < 8; ++o) {
        int rg = wave * 8 + o;
        int r = rg * 4 + a_rl;
        int cs = (lane & 15) ^ (r & 7);
        async_copy16(aBase + (size_t)r * 512 + cs * 4, &As[rg * 256]);
      }
      const unsigned short* bBase = Wt + (size_t)n0 * 512 + k0;
#pragma unroll
      for (int o = 0; o < 4; ++o) {
        int rg = wave * 4 + o;
        int r = rg * 8 + b_rl;
        async_copy16(bBase + (size_t)r * 512 + b_cs * 8, &Bs[rg * 512]);
      }
    }
    __syncthreads();

#pragma unroll
    for (int x = 0; x < 2; ++x) {
      bf16x8 a[4], bfr[4];
#pragma unroll
      for (int i = 0; i < 4; ++i) {
        int ra = wm + 16 * i + l15;
        int c0 = x * 8 + quad * 2;
        float4 f0 = *reinterpret_cast<const float4*>(&As[(ra * 16 + (c0 ^ (ra & 7))) * 4]);
        float4 f1 = *reinterpret_cast<const float4*>(&As[(ra * 16 + ((c0 + 1) ^ (ra & 7))) * 4]);
        union { bf16x8 v; unsigned short s[8]; } u;
        u.s[0] = f2bf(f0.x); u.s[1] = f2bf(f0.y); u.s[2] = f2bf(f0.z); u.s[3] = f2bf(f0.w);
        u.s[4] = f2bf(f1.x); u.s[5] = f2bf(f1.y); u.s[6] = f2bf(f1.z); u.s[7] = f2bf(f1.w);
        a[i] = u.v;
      }
#pragma unroll
      for (int j = 0; j < 4; ++j) {
        int rb = wn + 16 * j + l15;
        int cb = x * 4 + quad;
        bfr[j] = *reinterpret_cast<const bf16x8*>(&Bs[(rb * 8 + (cb ^ (rb & 7))) * 8]);
      }
#pragma unroll
      for (int i = 0; i < 4; ++i)
#pragma unroll
        for (int j = 0; j < 4; ++j)
          acc[i][j] = __builtin_amdgcn_mfma_f32_16x16x32_bf16(a[i], bfr[j], acc[i][j], 0, 0, 0);
    }
  }
#pragma unroll
  for (int i = 0; i < 4; ++i)
#pragma unroll
    for (int j = 0; j < 4; ++j)
#pragma unroll
      for (int r = 0; r < 4; ++r) {
        int m = m0 + wm + 16 * i + 4 * quad + r;
        int n = n0 + wn + 16 * j + l15;
        Y[(size_t)m * 512 + n] = __float2bfloat16(acc[i][j][r]);
      }
}

// ---------------------------------------------------------------- fused attention
// grid 512 (blk = bh*4 + chunk), 512 threads (8 waves x 32 q-rows), 16 s-tiles
// of 64. 2 blocks/CU co-resident; partials merged via fp32 HW atomics into a
// zero-initialized acc/rs buffer. sigma(s)=4*(s&15)+(s>>4) permutes the PV
// contraction axis (applied to both P cols and V^T rows).
__global__ __launch_bounds__(512, 4) void attn_kernel(const __hip_bfloat16* __restrict__ qg,
                                                      const __hip_bfloat16* __restrict__ kg,
                                                      const float* __restrict__ keyg,
                                                      float* __restrict__ accg,
                                                      float* __restrict__ rsg) {
  __shared__ unsigned short ks[64 * 64];  // k_tile[s][c], xor-chunk-swizzled (DMA)
  __shared__ unsigned short vs[64][66];   // v_tile transposed [c][sigma(s)]
  __shared__ unsigned short ps[256][72];  // attn tile [n][sigma(s)]
  __shared__ float red[8][64];            // cross-wave column-sum partials

  const int t = threadIdx.x;
  const int wave = t >> 6, lane = t & 63, l15 = lane & 15, quad = lane >> 4;
  const int blk = blockIdx.x, chunk = blk & 3, bh = blk >> 2, b = bh >> 3, h = bh & 7;

  // q fragments in registers: rows [32*wave, +32), A-layout A[m=l15][k=quad*8+j]
  bf16x8 qf[2][2];
#pragma unroll
  for (int i = 0; i < 2; ++i)
#pragma unroll
    for (int x = 0; x < 2; ++x) {
      const unsigned short* p = (const unsigned short*)qg +
          (size_t)(b * 256 + wave * 32 + 16 * i + l15) * 512 + h * 64 + x * 32 + quad * 8;
      qf[i][x] = *reinterpret_cast<const bf16x8*>(p);
    }

  // ones B-fragment for the MFMA rowsum (bf16 1.0 splat)
  union { bf16x8 f; int w[4]; } ones_u;
  ones_u.w[0] = 0x3F803F80; ones_u.w[1] = 0x3F803F80;
  ones_u.w[2] = 0x3F803F80; ones_u.w[3] = 0x3F803F80;
  const bf16x8 ones = ones_u.f;

  f32x4 oacc[2][4], rsacc[2];
#pragma unroll
  for (int i = 0; i < 2; ++i) {
    f32x4 z = {0.f, 0.f, 0.f, 0.f};
    rsacc[i] = z;
#pragma unroll
    for (int j = 0; j < 4; ++j) oacc[i][j] = z;
  }

  const int s0base = chunk * 1024;
  const int krow = lane >> 3, kchunk = (lane & 7) ^ krow;   // DMA swizzle lanes
  for (int it = 0; it < 16; ++it) {
    const int s0 = s0base + it * 64;
    __syncthreads();  // protect ks/vs/red from previous iteration readers
    {
      // k tile: one DMA issue per wave (8 rows x 8 chunks of 16B, xor-swizzled)
      const unsigned short* kbase = (const unsigned short*)kg + ((size_t)(b * 4096 + s0)) * 512 + h * 64;
      async_copy16(kbase + (size_t)(wave * 8 + krow) * 512 + kchunk * 8, &ks[wave * 512]);

      // v tile transposed + sigma-permuted, fp32 -> packed bf16.
      // c = lane (banks c mod 32 -> 2-way, free); k2 = s&15; sigma pair (s, s+16).
      const float* vbase = keyg + ((size_t)(b * 4096 + s0)) * 512 + h * 64;
      const int c = lane;
#pragma unroll
      for (int kk = 0; kk < 2; ++kk) {
        int k2 = wave + 8 * kk;                 // 0..15
#pragma unroll
        for (int p = 0; p < 2; ++p) {
          float va = vbase[(size_t)(32 * p + k2) * 512 + c];
          float vb = vbase[(size_t)(32 * p + 16 + k2) * 512 + c];
          *reinterpret_cast<u32*>(&vs[c][4 * k2 + 2 * p]) = pkbf(va, vb);
        }
      }
    }
    __syncthreads();

    // L = q @ k_tile^T  (D rows = n-local, cols = s-local)
    f32x4 L[2][4];
#pragma unroll
    for (int i = 0; i < 2; ++i)
#pragma unroll
      for (int j = 0; j < 4; ++j) { f32x4 z = {0.f, 0.f, 0.f, 0.f}; L[i][j] = z; }
#pragma unroll
    for (int x = 0; x < 2; ++x) {
      bf16x8 bfr[4];
#pragma unroll
      for (int j = 0; j < 4; ++j) {
        int rb = 16 * j + l15;
        int phys = (x * 4 + quad) ^ (rb & 7);
        bfr[j] = *reinterpret_cast<const bf16x8*>(&ks[rb * 64 + phys * 8]);
      }
#pragma unroll
      for (int i = 0; i < 2; ++i)
#pragma unroll
        for (int j = 0; j < 4; ++j)
          L[i][j] = __builtin_amdgcn_mfma_f32_16x16x32_bf16(qf[i][x], bfr[j], L[i][j], 0, 0, 0);
    }

    // exp(l/8); column (n) sums: per-lane, then quads, then 8 waves via LDS
    float csum[4] = {0.f, 0.f, 0.f, 0.f};
#pragma unroll
    for (int i = 0; i < 2; ++i)
#pragma unroll
      for (int j = 0; j < 4; ++j)
#pragma unroll
        for (int r = 0; r < 4; ++r) {
          float e = __expf(L[i][j][r] * 0.125f);
          L[i][j][r] = e;
          csum[j] += e;
        }
#pragma unroll
    for (int j = 0; j < 4; ++j) {
      float v = csum[j];
      v += __shfl_xor(v, 16);
      v += __shfl_xor(v, 32);
      csum[j] = v;
    }
    if (quad == 0) {
#pragma unroll
      for (int j = 0; j < 4; ++j) red[wave][16 * j + l15] = csum[j];
    }
    __syncthreads();
    float rcol[4];
#pragma unroll
    for (int j = 0; j < 4; ++j) {
      int s = 16 * j + l15;
      rcol[j] = 1.0f / (red[0][s] + red[1][s] + red[2][s] + red[3][s] +
                        red[4][s] + red[5][s] + red[6][s] + red[7][s]);
    }

    // normalize -> attn; write P tile packed (2x cvt_pk) at sigma-columns 4*l15
#pragma unroll
    for (int i = 0; i < 2; ++i)
#pragma unroll
      for (int r = 0; r < 4; ++r) {
        int nloc = wave * 32 + 16 * i + 4 * quad + r;
        u32 w0 = pkbf(L[i][0][r] * rcol[0], L[i][1][r] * rcol[1]);
        u32 w1 = pkbf(L[i][2][r] * rcol[2], L[i][3][r] * rcol[3]);
        u32* dst = reinterpret_cast<u32*>(&ps[nloc][4 * l15]);
        dst[0] = w0; dst[1] = w1;
      }

    // O += P @ V ; rowsum += P @ ones  (in sigma-space, permutation-invariant)
#pragma unroll
    for (int x = 0; x < 2; ++x) {
      bf16x8 ap[2], bv[4];
#pragma unroll
      for (int i = 0; i < 2; ++i)
        ap[i] = *reinterpret_cast<const bf16x8*>(&ps[wave * 32 + 16 * i + l15][x * 32 + quad * 8]);
#pragma unroll
      for (int j = 0; j < 4; ++j) {
        const int* vp = reinterpret_cast<const int*>(&vs[16 * j + l15][x * 32 + quad * 8]);
        union { bf16x8 f; int w[4]; } u;
        u.w[0] = vp[0]; u.w[1] = vp[1]; u.w[2] = vp[2]; u.w[3] = vp[3];
        bv[j] = u.f;
      }
#pragma unroll
      for (int i = 0; i < 2; ++i) {
#pragma unroll
        for (int j = 0; j < 4; ++j)
          oacc[i][j] = __builtin_amdgcn_mfma_f32_16x16x32_bf16(ap[i], bv[j], oacc[i][j], 0, 0, 0);
        rsacc[i] = __builtin_amdgcn_mfma_f32_16x16x32_bf16(ap[i], ones, rsacc[i], 0, 0, 0);
      }
    }
  }

  // merge partials via HW fp32 atomics (acc/rs zero-initialized in-stream)
  float* rsp = rsg + bh * 256;
  if (l15 == 0) {
#pragma unroll
    for (int i = 0; i < 2; ++i)
#pragma unroll
      for (int r = 0; r < 4; ++r)
        unsafeAtomicAdd(&rsp[wave * 32 + 16 * i + 4 * quad + r], rsacc[i][r]);
  }
  float* ap_ = accg + (size_t)bh * 16384;
#pragma unroll
  for (int i = 0; i < 2; ++i)
#pragma unroll
    for (int j = 0; j < 4; ++j)
#pragma unroll
      for (int r = 0; r < 4; ++r)
        unsafeAtomicAdd(&ap_[(wave * 32 + 16 * i + 4 * quad + r) * 64 + 16 * j + l15],
                        oacc[i][j][r]);
}

// ---------------------------------------------------------------- finalize: divide + write both outputs
__global__ __launch_bounds__(256) void finalize(const float* __restrict__ acc,
                                                const float* __restrict__ rs,
                                                float* __restrict__ out) {
  int idx = blockIdx.x * 256 + threadIdx.x;   // 0 .. 2097151
  int c = idx & 63, n = (idx >> 6) & 255, bh = idx >> 14;
  float v = acc[idx];
  float r = rs[bh * 256 + n];
  float o = v / fmaxf(r, 1.0f);
  int b = bh >> 3, h = bh & 7;
  size_t oi = ((size_t)(b * 256 + n)) * 512 + h * 64 + c;
  out[oi] = o;
  out[oi + 2097152] = o;
}

extern "C" void kernel_launch(void* const* d_in, const int* in_sizes, int n_in,
                              void* d_out, int out_size, void* d_ws, size_t ws_size,
                              hipStream_t stream) {
  const float* query = (const float*)d_in[0];   // [16,256,512]
  const float* key   = (const float*)d_in[1];   // [16,4096,512]
  const float* Wq    = (const float*)d_in[2];   // [512,512]
  const float* Wk    = (const float*)d_in[3];   // [512,512]
  float* out = (float*)d_out;
  char* ws = (char*)d_ws;

  // ws layout (bytes):
  unsigned short* WtQ = (unsigned short*)(ws);                 // 512*512*2   = 524288
  unsigned short* WtK = (unsigned short*)(ws + 524288);        // 524288
  __hip_bfloat16* qbf = (__hip_bfloat16*)(ws + 1048576);       // 4096*512*2  = 4194304
  __hip_bfloat16* kbf = (__hip_bfloat16*)(ws + 5242880);       // 65536*512*2 = 67108864
  float* accw = (float*)(ws + 72351744);                       // 128*256*64*4 = 8388608
  float* rsw  = (float*)(ws + 80740352);                       // 128*256*4    = 131072
  // total: 80,871,424 bytes

  prep_w<<<128, 256, 0, stream>>>(Wq, Wk, WtQ, WtK);
  gemm_xw<<<dim3(4, 32), 256, 0, stream>>>(query, WtQ, qbf);    // q = query @ Wq
  gemm_xw<<<dim3(4, 512), 256, 0, stream>>>(key, WtK, kbf);     // k = key @ Wk
  hipMemsetAsync(ws + 72351744, 0, 8519680, stream);            // zero acc+rs (contiguous)
  attn_kernel<<<512, 512, 0, stream>>>(qbf, kbf, key, accw, rsw);
  finalize<<<8192, 256, 0, stream>>>(accw, rsw, out);
}

// Round 6
// 333.465 us; speedup vs baseline: 1.1470x; 1.1470x over previous
//
#include <hip/hip_runtime.h>
#include <hip/hip_bf16.h>

// AssignAttention: B=16, N=256, S=4096, C=512, H=8, hd=64
// out[b,n,h*64+c] = sum_s softmax_n(q.kT/8)[n,s]/max(rowsum,1) * key[b,s,h*64+c]
// d_out = [out, out_style] (identical copies), fp32.

typedef __attribute__((ext_vector_type(8))) short bf16x8;
typedef __attribute__((ext_vector_type(4))) float f32x4;
typedef unsigned int u32;

__device__ __forceinline__ unsigned short f2bf(float f) {
  union { __hip_bfloat16 h; unsigned short u; } cv;
  cv.h = __float2bfloat16(f);
  return cv.u;
}

__device__ __forceinline__ u32 pkbf(float a, float b) {   // low=bf(a), high=bf(b)
  union { __hip_bfloat162 h; u32 u; } cv;
  cv.h = __float22bfloat162_rn(float2{a, b});
  return cv.u;
}

// async global->LDS, 16B per lane. LDS dest = wave-uniform base + lane*16.
__device__ __forceinline__ void async_copy16(const void* gptr, void* lptr) {
  __builtin_amdgcn_global_load_lds((const __attribute__((address_space(1))) u32*)gptr,
                                   (__attribute__((address_space(3))) u32*)lptr,
                                   16, 0, 0);
}

// ---------------------------------------------------------------- prep: Wt[n][k] = bf16(W[k][n])
__global__ __launch_bounds__(256) void prep_w(const float* __restrict__ Wq,
                                              const float* __restrict__ Wk,
                                              unsigned short* __restrict__ WtQ,
                                              unsigned short* __restrict__ WtK) {
  __shared__ float tile[64][65];
  const int blk = blockIdx.x;
  const float* W = (blk & 1) ? Wk : Wq;
  unsigned short* Wt = (blk & 1) ? WtK : WtQ;
  const int tb = blk >> 1;                     // 0..63
  const int k0 = (tb >> 3) * 64, n0 = (tb & 7) * 64;
  const int t = threadIdx.x;
  const int row = t >> 4, col4 = (t & 15) * 4;
#pragma unroll
  for (int i = 0; i < 4; ++i) {
    int r = i * 16 + row;
    float4 v = *reinterpret_cast<const float4*>(&W[(size_t)(k0 + r) * 512 + n0 + col4]);
    tile[r][col4 + 0] = v.x; tile[r][col4 + 1] = v.y;
    tile[r][col4 + 2] = v.z; tile[r][col4 + 3] = v.w;
  }
  __syncthreads();
#pragma unroll
  for (int i = 0; i < 4; ++i) {
    int r = i * 16 + row;                      // n-local output row
    short4 s;
    s.x = (short)f2bf(tile[col4 + 0][r]);
    s.y = (short)f2bf(tile[col4 + 1][r]);
    s.z = (short)f2bf(tile[col4 + 2][r]);
    s.w = (short)f2bf(tile[col4 + 3][r]);
    *reinterpret_cast<short4*>(&Wt[(size_t)(n0 + r) * 512 + k0 + col4]) = s;
  }
}

// ---------------------------------------------------------------- GEMM: Y[m][n] = bf16( X[m][:] @ Wt[n][:] )
// (unchanged from round 3 — swizzled DMA staging, conflicts verified gone)
__global__ __launch_bounds__(256, 3) void gemm_xw(const float* __restrict__ X,
                                                  const unsigned short* __restrict__ Wt,
                                                  __hip_bfloat16* __restrict__ Y) {
  __shared__ float As[128 * 64];            // 32 KB, swizzled chunk layout
  __shared__ unsigned short Bs[128 * 64];   // 16 KB, swizzled chunk layout
  const int t = threadIdx.x;
  const int wave = t >> 6, lane = t & 63, l15 = lane & 15, quad = lane >> 4;
  const int n0 = blockIdx.x * 128, m0 = blockIdx.y * 128;
  const int wm = (wave >> 1) * 64, wn = (wave & 1) * 64;

  const int a_rl = lane >> 4;                       // 0..3
  const int b_rl = lane >> 3;                       // 0..7
  const int b_cs = (lane & 7) ^ b_rl;               // source chunk (row&7 == b_rl)

  f32x4 acc[4][4];
#pragma unroll
  for (int i = 0; i < 4; ++i)
#pragma unroll
    for (int j = 0; j < 4; ++j) { f32x4 z = {0.f, 0.f, 0.f, 0.f}; acc[i][j] = z; }

  for (int k0 = 0; k0 < 512; k0 += 64) {
    __syncthreads();
    {
      const float* aBase = X + (size_t)m0 * 512 + k0;
#pragma unroll
      for (int o = 0; o < 8; ++o) {
        int rg = wave * 8 + o;
        int r = rg * 4 + a_rl;
        int cs = (lane & 15) ^ (r & 7);
        async_copy16(aBase + (size_t)r * 512 + cs * 4, &As[rg * 256]);
      }
      const unsigned short* bBase = Wt + (size_t)n0 * 512 + k0;
#pragma unroll
      for (int o = 0; o < 4; ++o) {
        int rg = wave * 4 + o;
        int r = rg * 8 + b_rl;
        async_copy16(bBase + (size_t)r * 512 + b_cs * 8, &Bs[rg * 512]);
      }
    }
    __syncthreads();

#pragma unroll
    for (int x = 0; x < 2; ++x) {
      bf16x8 a[4], bfr[4];
#pragma unroll
      for (int i = 0; i < 4; ++i) {
        int ra = wm + 16 * i + l15;
        int c0 = x * 8 + quad * 2;
        float4 f0 = *reinterpret_cast<const float4*>(&As[(ra * 16 + (c0 ^ (ra & 7))) * 4]);
        float4 f1 = *reinterpret_cast<const float4*>(&As[(ra * 16 + ((c0 + 1) ^ (ra & 7))) * 4]);
        union { bf16x8 v; unsigned short s[8]; } u;
        u.s[0] = f2bf(f0.x); u.s[1] = f2bf(f0.y); u.s[2] = f2bf(f0.z); u.s[3] = f2bf(f0.w);
        u.s[4] = f2bf(f1.x); u.s[5] = f2bf(f1.y); u.s[6] = f2bf(f1.z); u.s[7] = f2bf(f1.w);
        a[i] = u.v;
      }
#pragma unroll
      for (int j = 0; j < 4; ++j) {
        int rb = wn + 16 * j + l15;
        int cb = x * 4 + quad;
        bfr[j] = *reinterpret_cast<const bf16x8*>(&Bs[(rb * 8 + (cb ^ (rb & 7))) * 8]);
      }
#pragma unroll
      for (int i = 0; i < 4; ++i)
#pragma unroll
        for (int j = 0; j < 4; ++j)
          acc[i][j] = __builtin_amdgcn_mfma_f32_16x16x32_bf16(a[i], bfr[j], acc[i][j], 0, 0, 0);
    }
  }
#pragma unroll
  for (int i = 0; i < 4; ++i)
#pragma unroll
    for (int j = 0; j < 4; ++j)
#pragma unroll
      for (int r = 0; r < 4; ++r) {
        int m = m0 + wm + 16 * i + 4 * quad + r;
        int n = n0 + wn + 16 * j + l15;
        Y[(size_t)m * 512 + n] = __float2bfloat16(acc[i][j][r]);
      }
}

// ---------------------------------------------------------------- fused attention (swapped-operand)
// grid 256 (blk = bh*2 + chunk), 512 threads (8 waves), 16 iterations x 128 s.
// L^T = K.Q^T orientation: D[s][n] has n on l15 -> column softmax over n is
// fully within-wave (no red buffer, no softmax barrier). Wave w owns s-slice
// [16w,16w+16) of the tile; k frags in registers (global b128, prefetched);
// q in LDS once (xor-chunk swizzle); P written to LDS in A-layout (b64,
// swizzled); PV + ones-rowsum n-partitioned per wave (jt'=2w,2w+1) -> disjoint
// flush, no atomics. 2 barriers per 128-s iteration.
__global__ __launch_bounds__(512, 2) void attn_kernel(const __hip_bfloat16* __restrict__ qg,
                                                      const __hip_bfloat16* __restrict__ kg,
                                                      const float* __restrict__ keyg,
                                                      float* __restrict__ accg,
                                                      float* __restrict__ rsg) {
  __shared__ unsigned short qs[256 * 64];    // q[n][c], 16B-chunk phys = cc ^ (n&7)   (32 KB)
  __shared__ unsigned short vs[64 * 128];    // v^T[c][s], chunk phys = sc ^ (c&7)     (16 KB)
  __shared__ unsigned short pst[256 * 128];  // P[n][s],  chunk phys = sc ^ (n&7)      (64 KB)

  const int t = threadIdx.x;
  const int wave = t >> 6, lane = t & 63, l15 = lane & 15, quad = lane >> 4;
  const int blk = blockIdx.x, chunk = blk & 1, bh = blk >> 1, b = bh >> 3, h = bh & 7;
  const int l7 = l15 & 7;

  // ---- stage qs (once): 4 b128 per thread, coalesced 128B segments
  {
    const unsigned short* qbase = (const unsigned short*)qg + (size_t)(b * 256) * 512 + h * 64;
#pragma unroll
    for (int i = 0; i < 4; ++i) {
      int lin = i * 512 + t;
      int n = lin >> 3, cc = lin & 7, phys = cc ^ (n & 7);
      bf16x8 v = *reinterpret_cast<const bf16x8*>(qbase + (size_t)n * 512 + cc * 8);
      *reinterpret_cast<bf16x8*>(&qs[n * 64 + phys * 8]) = v;
    }
  }

  const unsigned short* kbase = (const unsigned short*)kg + (size_t)(b * 4096 + chunk * 2048) * 512 + h * 64;
  const float* vbase = keyg + (size_t)(b * 4096 + chunk * 2048) * 512 + h * 64;

  // ---- prefetch k (regs) and v (regs) for it=0
  bf16x8 kc0 = *reinterpret_cast<const bf16x8*>(kbase + (size_t)(16 * wave + l15) * 512 + quad * 8);
  bf16x8 kc1 = *reinterpret_cast<const bf16x8*>(kbase + (size_t)(16 * wave + l15) * 512 + 32 + quad * 8);
  float vbuf[16];
#pragma unroll
  for (int half = 0; half < 2; ++half) {
    int sc = wave + 8 * half;
#pragma unroll
    for (int j = 0; j < 8; ++j)
      vbuf[half * 8 + j] = vbase[(size_t)(sc * 8 + j) * 512 + lane];
  }

  union { bf16x8 f; int w[4]; } ones_u;
  ones_u.w[0] = 0x3F803F80; ones_u.w[1] = 0x3F803F80;
  ones_u.w[2] = 0x3F803F80; ones_u.w[3] = 0x3F803F80;
  const bf16x8 ones = ones_u.f;

  f32x4 oacc[2][4], rsacc[2];
#pragma unroll
  for (int i = 0; i < 2; ++i) {
    f32x4 z = {0.f, 0.f, 0.f, 0.f};
    rsacc[i] = z;
#pragma unroll
    for (int j = 0; j < 4; ++j) oacc[i][j] = z;
  }

  __syncthreads();   // qs visible

  for (int it = 0; it < 16; ++it) {
    // ---- QK^T (swapped): L[jt] = D[s16 x n16], A = k regs, B = q from LDS
    f32x4 L[16];
#pragma unroll
    for (int jt = 0; jt < 16; ++jt) { f32x4 z = {0.f, 0.f, 0.f, 0.f}; L[jt] = z; }
#pragma unroll
    for (int x = 0; x < 2; ++x) {
      bf16x8 kf = x ? kc1 : kc0;
#pragma unroll
      for (int jt = 0; jt < 16; ++jt) {
        bf16x8 bq = *reinterpret_cast<const bf16x8*>(
            &qs[(16 * jt + l15) * 64 + ((4 * x + quad) ^ l7) * 8]);
        L[jt] = __builtin_amdgcn_mfma_f32_16x16x32_bf16(kf, bq, L[jt], 0, 0, 0);
      }
    }

    // ---- prefetch next k (old regs dead)
    const int nit = (it < 15) ? it + 1 : 15;
    kc0 = *reinterpret_cast<const bf16x8*>(kbase + (size_t)(nit * 128 + 16 * wave + l15) * 512 + quad * 8);
    kc1 = *reinterpret_cast<const bf16x8*>(kbase + (size_t)(nit * 128 + 16 * wave + l15) * 512 + 32 + quad * 8);

    // ---- exp + within-wave column softmax (sum over n = jt in-lane + shfl over l15)
    float cs0 = 0.f, cs1 = 0.f, cs2 = 0.f, cs3 = 0.f;
#pragma unroll
    for (int jt = 0; jt < 16; ++jt) {
      float e0 = __expf(L[jt][0] * 0.125f);
      float e1 = __expf(L[jt][1] * 0.125f);
      float e2 = __expf(L[jt][2] * 0.125f);
      float e3 = __expf(L[jt][3] * 0.125f);
      L[jt][0] = e0; L[jt][1] = e1; L[jt][2] = e2; L[jt][3] = e3;
      cs0 += e0; cs1 += e1; cs2 += e2; cs3 += e3;
    }
#pragma unroll
    for (int m = 1; m <= 8; m <<= 1) {
      cs0 += __shfl_xor(cs0, m);
      cs1 += __shfl_xor(cs1, m);
      cs2 += __shfl_xor(cs2, m);
      cs3 += __shfl_xor(cs3, m);
    }
    const float ri0 = 1.0f / cs0, ri1 = 1.0f / cs1, ri2 = 1.0f / cs2, ri3 = 1.0f / cs3;

    __syncthreads();   // SYNC1: prev iteration's PV readers done with vs/pst

    // ---- stage vs from prefetched vbuf: one b128 per half, chunk-swizzled
#pragma unroll
    for (int half = 0; half < 2; ++half) {
      int sc = wave + 8 * half;
      uint4 w;
      w.x = pkbf(vbuf[half * 8 + 0], vbuf[half * 8 + 1]);
      w.y = pkbf(vbuf[half * 8 + 2], vbuf[half * 8 + 3]);
      w.z = pkbf(vbuf[half * 8 + 4], vbuf[half * 8 + 5]);
      w.w = pkbf(vbuf[half * 8 + 6], vbuf[half * 8 + 7]);
      *reinterpret_cast<uint4*>(&vs[lane * 128 + (sc ^ (lane & 7)) * 8]) = w;
    }

    // ---- write P[n][s] (A-layout rows), b64 chunk-swizzled
    {
      const int scw = 2 * wave + (quad >> 1);           // 16B-chunk of this lane's s
      const int half8 = (quad & 1) * 4;                 // b64 half within chunk
#pragma unroll
      for (int jt = 0; jt < 16; ++jt) {
        uint2 w;
        w.x = pkbf(L[jt][0] * ri0, L[jt][1] * ri1);
        w.y = pkbf(L[jt][2] * ri2, L[jt][3] * ri3);
        int row = 16 * jt + l15;
        *reinterpret_cast<uint2*>(&pst[row * 128 + ((scw ^ l7) * 8) + half8]) = w;
      }
    }

    __syncthreads();   // SYNC2: vs + pst visible

    // ---- prefetch next v (consumed next iteration)
#pragma unroll
    for (int half = 0; half < 2; ++half) {
      int sc = wave + 8 * half;
#pragma unroll
      for (int j = 0; j < 8; ++j)
        vbuf[half * 8 + j] = vbase[(size_t)(nit * 128 + sc * 8 + j) * 512 + lane];
    }

    // ---- PV + ones-rowsum, n-partitioned: wave owns jt' = 2w, 2w+1
#pragma unroll
    for (int kc = 0; kc < 4; ++kc) {
      bf16x8 bv[4];
#pragma unroll
      for (int jc = 0; jc < 4; ++jc)
        bv[jc] = *reinterpret_cast<const bf16x8*>(
            &vs[(16 * jc + l15) * 128 + ((4 * kc + quad) ^ l7) * 8]);
#pragma unroll
      for (int jtl = 0; jtl < 2; ++jtl) {
        int rowp = 16 * (2 * wave + jtl) + l15;
        bf16x8 ap = *reinterpret_cast<const bf16x8*>(
            &pst[rowp * 128 + ((4 * kc + quad) ^ l7) * 8]);
#pragma unroll
        for (int jc = 0; jc < 4; ++jc)
          oacc[jtl][jc] = __builtin_amdgcn_mfma_f32_16x16x32_bf16(ap, bv[jc], oacc[jtl][jc], 0, 0, 0);
        rsacc[jtl] = __builtin_amdgcn_mfma_f32_16x16x32_bf16(ap, ones, rsacc[jtl], 0, 0, 0);
      }
    }
  }

  // ---- flush per-chunk partials (disjoint n per wave, disjoint chunk regions)
  float* rsp = rsg + chunk * 32768 + bh * 256;
  if (l15 == 0) {
#pragma unroll
    for (int jtl = 0; jtl < 2; ++jtl)
#pragma unroll
      for (int r = 0; r < 4; ++r)
        rsp[16 * (2 * wave + jtl) + 4 * quad + r] = rsacc[jtl][r];
  }
  float* ap_ = accg + (size_t)chunk * 2097152 + (size_t)bh * 16384;
#pragma unroll
  for (int jtl = 0; jtl < 2; ++jtl)
#pragma unroll
    for (int jc = 0; jc < 4; ++jc)
#pragma unroll
      for (int r = 0; r < 4; ++r)
        ap_[(16 * (2 * wave + jtl) + 4 * quad + r) * 64 + 16 * jc + l15] = oacc[jtl][jc][r];
}

// ---------------------------------------------------------------- finalize: divide + write both outputs
__global__ __launch_bounds__(256) void finalize(const float* __restrict__ acc,
                                                const float* __restrict__ rs,
                                                float* __restrict__ out) {
  int idx = blockIdx.x * 256 + threadIdx.x;   // 0 .. 2097151
  int c = idx & 63, n = (idx >> 6) & 255, bh = idx >> 14;
  float v = acc[idx] + acc[idx + 2097152];
  float r = rs[bh * 256 + n] + rs[32768 + bh * 256 + n];
  float o = v / fmaxf(r, 1.0f);
  int b = bh >> 3, h = bh & 7;
  size_t oi = ((size_t)(b * 256 + n)) * 512 + h * 64 + c;
  out[oi] = o;
  out[oi + 2097152] = o;
}

extern "C" void kernel_launch(void* const* d_in, const int* in_sizes, int n_in,
                              void* d_out, int out_size, void* d_ws, size_t ws_size,
                              hipStream_t stream) {
  const float* query = (const float*)d_in[0];   // [16,256,512]
  const float* key   = (const float*)d_in[1];   // [16,4096,512]
  const float* Wq    = (const float*)d_in[2];   // [512,512]
  const float* Wk    = (const float*)d_in[3];   // [512,512]
  float* out = (float*)d_out;
  char* ws = (char*)d_ws;

  // ws layout (bytes):
  unsigned short* WtQ = (unsigned short*)(ws);                 // 512*512*2   = 524288
  unsigned short* WtK = (unsigned short*)(ws + 524288);        // 524288
  __hip_bfloat16* qbf = (__hip_bfloat16*)(ws + 1048576);       // 4096*512*2  = 4194304
  __hip_bfloat16* kbf = (__hip_bfloat16*)(ws + 5242880);       // 65536*512*2 = 67108864
  float* accw = (float*)(ws + 72351744);                       // 2*128*256*64*4 = 16777216
  float* rsw  = (float*)(ws + 89128960);                       // 2*128*256*4    = 262144
  // total: 89,391,104 bytes

  prep_w<<<128, 256, 0, stream>>>(Wq, Wk, WtQ, WtK);
  gemm_xw<<<dim3(4, 32), 256, 0, stream>>>(query, WtQ, qbf);    // q = query @ Wq
  gemm_xw<<<dim3(4, 512), 256, 0, stream>>>(key, WtK, kbf);     // k = key @ Wk
  attn_kernel<<<256, 512, 0, stream>>>(qbf, kbf, key, accw, rsw);
  finalize<<<8192, 256, 0, stream>>>(accw, rsw, out);
}